// Round 12
// baseline (316.291 us; speedup 1.0000x reference)
//
#include <hip/hip_runtime.h>
#include <hip/hip_fp16.h>
#include <hip/hip_cooperative_groups.h>
#include <math.h>

namespace cg = cooperative_groups;

// ---------------------------------------------------------------------------
// GCN 3-layer forward on MI355X.
// Per layer (D=64):
//   hs[i,:] = fp16( dinv[i] * (x[i,:] @ W) )
//   out[i,:]= dinv[i] * (hs[i,:] + sum_{e: dst(e)=i} hs[src(e),:]) + b
//   optional LeakyReLU(0.01);   dinv[i] = rsqrt(1 + indeg(i))
//
// Round-12:
//  - W B-fragments loaded straight from global into registers (16 scalar
//    L1-hot loads in the exact MFMA B layout).  Deletes stage_wt, whose
//    column-scatter LDS writes were ~8-way bank conflicts (6M conflict
//    cycles/dispatch in r11).  LDS 11.8KB -> 2.4KB.
//  - CSR build collapsed into ONE cooperative kernel (hist -> column scan ->
//    scatter -> bucket sort with grid.sync between phases); per-block shfl
//    scan of `total` replaces the base_scan kernel.  Removes 4 launches and
//    4 full-grid drains.
// Aggs (r8) remain at ~87% of the per-CU streaming byte rate.
// ---------------------------------------------------------------------------

constexpr int SHIFT = 8;          // bucket = dst >> 8  (256 nodes per bucket)
constexpr int CHUNK = 4096;       // edges per hist/scatter block
constexpr int BCAP  = 5120;       // bucket staging capacity (mean 4096, sd 64)

typedef _Float16 half8 __attribute__((ext_vector_type(8)));
typedef float floatx4 __attribute__((ext_vector_type(4)));

// Exclusive scan of v over 256 threads (2 barriers).
__device__ inline int scan256(int v, int tid, int* wsum, int* total) {
    int lane = tid & 63, w = tid >> 6;
    int inc = v;
#pragma unroll
    for (int off = 1; off < 64; off <<= 1) {
        int t = __shfl_up(inc, off);
        if (lane >= off) inc += t;
    }
    if (lane == 63) wsum[w] = inc;
    __syncthreads();
    int s0 = wsum[0], s1 = wsum[1], s2 = wsum[2], s3 = wsum[3];
    __syncthreads();
    int base = (w > 0 ? s0 : 0) + (w > 1 ? s1 : 0) + (w > 2 ? s2 : 0);
    *total = s0 + s1 + s2 + s3;
    return base + (inc - v);
}

// ---- cooperative CSR build: hist -> col-scan -> scatter -> bucket sort ----
// record = (dst & 255) << 24 | src  (src < 2^17); col[] = src byte offsets.
__global__ void k_build(const int* __restrict__ src, const int* __restrict__ dst,
                        int E, int n, int NB, int B1,
                        int* __restrict__ Bh, int* __restrict__ Bc,
                        int* __restrict__ total, unsigned* __restrict__ ebuf,
                        int* __restrict__ col, int* __restrict__ row_ptr) {
    cg::grid_group grid = cg::this_grid();
    __shared__ union {
        struct { unsigned srec[CHUNK]; int spos[CHUNK]; } sc;   // 32 KB
        struct { unsigned raw[BCAP]; int sorted[BCAP]; } so;    // 40 KB
    } U;
    __shared__ int h[512];
    __shared__ int cur[512];
    __shared__ int gb[512];
    __shared__ int wsum[4];
    int tid = threadIdx.x;
    int blk = blockIdx.x;

    // ---- phase A: per-chunk bucket histogram ----
    if (blk < B1) {
        for (int i = tid; i < 512; i += 256) h[i] = 0;
        __syncthreads();
        int s = blk * CHUNK, e = min(s + CHUNK, E);
        for (int i = s + tid; i < e; i += 256) atomicAdd(&h[dst[i] >> SHIFT], 1);
        __syncthreads();
        for (int i = tid; i < NB; i += 256) {
            int v = h[i];
            Bh[(size_t)blk * NB + i] = v;
            Bc[(size_t)blk * NB + i] = v;
        }
    }
    grid.sync();

    // ---- phase B: per-bucket exclusive scan down the chunk axis ----
    if (blk < NB) {
        int carry = 0;
        for (int j0 = 0; j0 < B1; j0 += 256) {
            int j = j0 + tid;
            int v = (j < B1) ? Bh[(size_t)j * NB + blk] : 0;
            int tot;
            int ex = scan256(v, tid, wsum, &tot);
            if (j < B1) Bh[(size_t)j * NB + blk] = ex + carry;
            carry += tot;
        }
        if (tid == 0) total[blk] = carry;
    }
    grid.sync();

    // ---- phase C: LDS-binned scatter into bucket-contiguous ebuf ----
    if (blk < B1) {
        int b0 = 2 * tid, b1i = 2 * tid + 1;
        int t0 = (b0 < NB) ? total[b0] : 0;
        int t1 = (b1i < NB) ? total[b1i] : 0;
        int tot;
        int exb = scan256(t0 + t1, tid, wsum, &tot);   // bucket bases
        int base0 = exb, base1 = exb + t0;
        int c0 = (b0 < NB) ? Bc[(size_t)blk * NB + b0] : 0;
        int c1 = (b1i < NB) ? Bc[(size_t)blk * NB + b1i] : 0;
        int exl = scan256(c0 + c1, tid, wsum, &tot);   // local chunk offsets
        if (b0 < NB) {
            cur[b0] = exl;
            gb[b0]  = base0 + Bh[(size_t)blk * NB + b0] - exl;
        }
        if (b1i < NB) {
            int l1 = exl + c0;
            cur[b1i] = l1;
            gb[b1i]  = base1 + Bh[(size_t)blk * NB + b1i] - l1;
        }
        __syncthreads();
        int s = blk * CHUNK, e = min(s + CHUNK, E);
        for (int i = s + tid; i < e; i += 256) {
            int d = dst[i];
            int b = d >> SHIFT;
            unsigned rec = ((unsigned)(d & 255) << 24) | (unsigned)src[i];
            int lpos = atomicAdd(&cur[b], 1);
            U.sc.srec[lpos] = rec;
            U.sc.spos[lpos] = gb[b] + lpos;
        }
        __syncthreads();
        int cntE = e - s;
        for (int t = tid; t < cntE; t += 256) ebuf[U.sc.spos[t]] = U.sc.srec[t];
    }
    grid.sync();

    // ---- phase D: per-bucket counting sort -> row_ptr + col ----
    if (blk < NB) {
        int b0 = 2 * tid, b1i = 2 * tid + 1;
        int t0 = (b0 < NB) ? total[b0] : 0;
        int t1 = (b1i < NB) ? total[b1i] : 0;
        int tot;
        int exb = scan256(t0 + t1, tid, wsum, &tot);
        if (b0 < NB) gb[b0] = exb;
        if (b1i < NB) gb[b1i] = exb + t0;
        h[tid] = 0;
        __syncthreads();
        int s = gb[blk];
        int len = total[blk];
        int e = s + len;
        if (len <= BCAP) {
            for (int t = tid; t < len; t += 256) {
                unsigned v = ebuf[s + t];          // single global read
                U.so.raw[t] = v;
                atomicAdd(&h[v >> 24], 1);
            }
            __syncthreads();
            int ex = scan256(h[tid], tid, wsum, &tot);
            int node = (blk << SHIFT) | tid;
            if (node < n) row_ptr[node] = s + ex;
            cur[tid] = ex;
            __syncthreads();
            for (int t = tid; t < len; t += 256) {
                unsigned v = U.so.raw[t];
                int lpos = atomicAdd(&cur[v >> 24], 1);
                U.so.sorted[lpos] = (int)((v & 0x00FFFFFFu) << 7);  // src*128
            }
            __syncthreads();
            for (int t = tid; t < len; t += 256) col[s + t] = U.so.sorted[t];
        } else {  // statistical-impossibility fallback
            for (int i = s + tid; i < e; i += 256) atomicAdd(&h[ebuf[i] >> 24], 1);
            __syncthreads();
            int ex = scan256(h[tid], tid, wsum, &tot);
            int node = (blk << SHIFT) | tid;
            if (node < n) row_ptr[node] = s + ex;
            cur[tid] = ex;
            __syncthreads();
            for (int i = s + tid; i < e; i += 256) {
                unsigned v = ebuf[i];
                int lpos = atomicAdd(&cur[v >> 24], 1);
                col[s + lpos] = (int)((v & 0x00FFFFFFu) << 7);
            }
        }
        if (blk == 0 && tid == 0) row_ptr[n] = E;
    }
}

// ---- B-fragment (W columns) loaded straight from global into registers ----
// mfma_f32_16x16x32_f16 B layout: lane l holds B[k=(l>>4)*8+j][col=l&15];
// wave w covers output cols [16w,16w+16).  16-lane groups read 64B/row ->
// coalesced; W is L1-hot after the first wave.
__device__ inline void load_bfrag(const float* __restrict__ W, int tid,
                                  half8* b1, half8* b2) {
    int lane = tid & 63;
    int colg = (tid >> 6) * 16 + (lane & 15);
    int k0 = (lane >> 4) * 8;
    half8 x1, x2;
#pragma unroll
    for (int j = 0; j < 8; j++) {
        x1[j] = (_Float16)W[(k0 + j) * 64 + colg];
        x2[j] = (_Float16)W[(k0 + 32 + j) * 64 + colg];
    }
    *b1 = x1;
    *b2 = x2;
}

// ---- shared MFMA tail: rows(16x64 fp16 in LDS) x b-frags -> fp16 HS -------
__device__ inline void mfma_rows_store(const _Float16* rowS, const float* dinvS,
                                       half8 b1, half8 b2, int n, int blockRow0,
                                       int tid, __half* __restrict__ HSn) {
    int w = tid >> 6;
    int lane = tid & 63;
    int ar = lane & 15;
    int ks = lane >> 4;

    half8 a1 = *(const half8*)&rowS[ar * 72 + ks * 8];
    half8 a2 = *(const half8*)&rowS[ar * 72 + 32 + ks * 8];

    floatx4 acc = {0.f, 0.f, 0.f, 0.f};
    acc = __builtin_amdgcn_mfma_f32_16x16x32_f16(a1, b1, acc, 0, 0, 0);
    acc = __builtin_amdgcn_mfma_f32_16x16x32_f16(a2, b2, acc, 0, 0, 0);

    int node0 = (lane >> 4) * 4;
    float4 dv4 = *(const float4*)&dinvS[node0];
    int colg = w * 16 + (lane & 15);
    int base_node = blockRow0 + node0;
#pragma unroll
    for (int reg = 0; reg < 4; reg++) {
        int node_g = base_node + reg;
        if (node_g < n) {
            float dv = (reg == 0) ? dv4.x : (reg == 1) ? dv4.y : (reg == 2) ? dv4.z : dv4.w;
            HSn[(size_t)node_g * 64 + colg] = __float2half(acc[reg] * dv);
        }
    }
}

// ---- layer-1 GEMM via MFMA: HS = fp16(dinv * (X @ W)) ----------------------
__global__ void k_gemm_scale(const float* __restrict__ X, const float* __restrict__ W,
                             const int* __restrict__ row_ptr, int n,
                             __half* __restrict__ HS) {
    __shared__ _Float16 rowS[16 * 72];
    __shared__ float dinvS[16];
    int tid = threadIdx.x;

    half8 b1, b2;
    load_bfrag(W, tid, &b1, &b2);

    int g = tid >> 4;
    int c = tid & 15;
    int gid = blockIdx.x * 16 + g;
    if (gid < n) {
        float4 xv = *(const float4*)&X[(size_t)gid * 64 + c * 4];
        __half2 h0 = __floats2half2_rn(xv.x, xv.y);
        __half2 h1 = __floats2half2_rn(xv.z, xv.w);
        uint2 pack;
        pack.x = *(const unsigned int*)&h0;
        pack.y = *(const unsigned int*)&h1;
        *(uint2*)&rowS[g * 72 + c * 4] = pack;
        if (c == 0)
            dinvS[g] = rsqrtf(1.0f + (float)(row_ptr[gid + 1] - row_ptr[gid]));
    }
    __syncthreads();
    mfma_rows_store(rowS, dinvS, b1, b2, n, blockIdx.x * 16, tid, HS);
}

__device__ inline float4 cvt_h4(uint2 v) {
    float2 f0 = __half22float2(*(__half2*)&v.x);
    float2 f1 = __half22float2(*(__half2*)&v.y);
    return make_float4(f0.x, f0.y, f1.x, f1.y);
}

__device__ inline uint2 ld_row(const char* HSb, int boff, int c) {
    return *(const uint2*)(HSb + boff + (c << 3));
}

// Gather-aggregate one node's row: s = hs[self] + sum hs[src].  16-lane
// group, 8 gathers in flight (main), 4-batch, predicated singles.
__device__ inline float4 agg_row(const char* __restrict__ HSb,
                                 const int* __restrict__ col,
                                 int gid, int c, int r0, int r1) {
    float4 a0 = cvt_h4(*(const uint2*)(HSb + ((size_t)gid << 7) + (c << 3)));
    float4 a1 = make_float4(0.f, 0.f, 0.f, 0.f);
    float4 a2 = a1, a3 = a1;
    int e = r0;
    for (; e + 8 <= r1; e += 8) {
        int s0 = col[e + 0], s1 = col[e + 1], s2 = col[e + 2], s3 = col[e + 3];
        int s4 = col[e + 4], s5 = col[e + 5], s6 = col[e + 6], s7 = col[e + 7];
        uint2 v0 = ld_row(HSb, s0, c), v1 = ld_row(HSb, s1, c);
        uint2 v2 = ld_row(HSb, s2, c), v3 = ld_row(HSb, s3, c);
        uint2 v4 = ld_row(HSb, s4, c), v5 = ld_row(HSb, s5, c);
        uint2 v6 = ld_row(HSb, s6, c), v7 = ld_row(HSb, s7, c);
        float4 f0 = cvt_h4(v0), f1 = cvt_h4(v1), f2 = cvt_h4(v2), f3 = cvt_h4(v3);
        float4 f4 = cvt_h4(v4), f5 = cvt_h4(v5), f6 = cvt_h4(v6), f7 = cvt_h4(v7);
        a0.x += f0.x; a0.y += f0.y; a0.z += f0.z; a0.w += f0.w;
        a1.x += f1.x; a1.y += f1.y; a1.z += f1.z; a1.w += f1.w;
        a2.x += f2.x; a2.y += f2.y; a2.z += f2.z; a2.w += f2.w;
        a3.x += f3.x; a3.y += f3.y; a3.z += f3.z; a3.w += f3.w;
        a0.x += f4.x; a0.y += f4.y; a0.z += f4.z; a0.w += f4.w;
        a1.x += f5.x; a1.y += f5.y; a1.z += f5.z; a1.w += f5.w;
        a2.x += f6.x; a2.y += f6.y; a2.z += f6.z; a2.w += f6.w;
        a3.x += f7.x; a3.y += f7.y; a3.z += f7.z; a3.w += f7.w;
    }
    if (e + 4 <= r1) {
        int s0 = col[e + 0], s1 = col[e + 1], s2 = col[e + 2], s3 = col[e + 3];
        uint2 v0 = ld_row(HSb, s0, c), v1 = ld_row(HSb, s1, c);
        uint2 v2 = ld_row(HSb, s2, c), v3 = ld_row(HSb, s3, c);
        float4 f0 = cvt_h4(v0), f1 = cvt_h4(v1), f2 = cvt_h4(v2), f3 = cvt_h4(v3);
        a0.x += f0.x; a0.y += f0.y; a0.z += f0.z; a0.w += f0.w;
        a1.x += f1.x; a1.y += f1.y; a1.z += f1.z; a1.w += f1.w;
        a2.x += f2.x; a2.y += f2.y; a2.z += f2.z; a2.w += f2.w;
        a3.x += f3.x; a3.y += f3.y; a3.z += f3.z; a3.w += f3.w;
        e += 4;
    }
    if (e + 0 < r1) {
        float4 f = cvt_h4(ld_row(HSb, col[e + 0], c));
        a0.x += f.x; a0.y += f.y; a0.z += f.z; a0.w += f.w;
    }
    if (e + 1 < r1) {
        float4 f = cvt_h4(ld_row(HSb, col[e + 1], c));
        a1.x += f.x; a1.y += f.y; a1.z += f.z; a1.w += f.w;
    }
    if (e + 2 < r1) {
        float4 f = cvt_h4(ld_row(HSb, col[e + 2], c));
        a2.x += f.x; a2.y += f.y; a2.z += f.z; a2.w += f.w;
    }
    float4 s;
    s.x = (a0.x + a1.x) + (a2.x + a3.x);
    s.y = (a0.y + a1.y) + (a2.y + a3.y);
    s.z = (a0.z + a1.z) + (a2.z + a3.z);
    s.w = (a0.w + a1.w) + (a2.w + a3.w);
    return s;
}

// ---- fused: agg epilogue + next-layer GEMM (MFMA) -> fp16 hs_next ---------
template <bool RELU>
__global__ void k_agg_gemm(const __half* __restrict__ HS, const int* __restrict__ row_ptr,
                           const int* __restrict__ col, const float* __restrict__ bias,
                           const float* __restrict__ Wn, int n,
                           __half* __restrict__ HSn) {
    __shared__ _Float16 rowS[16 * 72];
    __shared__ float dinvS[16];
    int tid = threadIdx.x;

    half8 b1, b2;
    load_bfrag(Wn, tid, &b1, &b2);

    int g = tid >> 4;
    int c = tid & 15;
    int gid = blockIdx.x * 16 + g;

    if (gid < n) {
        const char* __restrict__ HSb = (const char*)HS;
        int r0 = row_ptr[gid];
        int r1 = row_ptr[gid + 1];
        float4 s = agg_row(HSb, col, gid, c, r0, r1);
        float deg = 1.0f + (float)(r1 - r0);
        float dinv = rsqrtf(deg);
        float4 bv = *(const float4*)&bias[4 * c];
        float vx = dinv * s.x + bv.x;
        float vy = dinv * s.y + bv.y;
        float vz = dinv * s.z + bv.z;
        float vw = dinv * s.w + bv.w;
        if (RELU) {
            vx = (vx >= 0.f) ? vx : 0.01f * vx;
            vy = (vy >= 0.f) ? vy : 0.01f * vy;
            vz = (vz >= 0.f) ? vz : 0.01f * vz;
            vw = (vw >= 0.f) ? vw : 0.01f * vw;
        }
        __half2 h0 = __floats2half2_rn(vx, vy);
        __half2 h1 = __floats2half2_rn(vz, vw);
        uint2 pack;
        pack.x = *(const unsigned int*)&h0;
        pack.y = *(const unsigned int*)&h1;
        *(uint2*)&rowS[g * 72 + c * 4] = pack;
        if (c == 0) dinvS[g] = dinv;
    }
    __syncthreads();
    mfma_rows_store(rowS, dinvS, b1, b2, n, blockIdx.x * 16, tid, HSn);
}

// ---- final layer: agg + bias + LeakyReLU -> fp32 out ----------------------
__global__ void k_agg_out(const __half* __restrict__ HS, const int* __restrict__ row_ptr,
                          const int* __restrict__ col, const float* __restrict__ bias,
                          int n, float* __restrict__ out) {
    int gid = (int)((blockIdx.x * (unsigned)blockDim.x + threadIdx.x) >> 4);
    if (gid >= n) return;
    int c = threadIdx.x & 15;
    const char* __restrict__ HSb = (const char*)HS;
    int r0 = row_ptr[gid];
    int r1 = row_ptr[gid + 1];
    float4 s = agg_row(HSb, col, gid, c, r0, r1);
    float deg = 1.0f + (float)(r1 - r0);
    float dinv = rsqrtf(deg);
    float4 bv = *(const float4*)&bias[4 * c];
    float vx = dinv * s.x + bv.x;
    float vy = dinv * s.y + bv.y;
    float vz = dinv * s.z + bv.z;
    float vw = dinv * s.w + bv.w;
    vx = (vx >= 0.f) ? vx : 0.01f * vx;
    vy = (vy >= 0.f) ? vy : 0.01f * vy;
    vz = (vz >= 0.f) ? vz : 0.01f * vz;
    vw = (vw >= 0.f) ? vw : 0.01f * vw;
    *(float4*)&out[(size_t)gid * 64 + 4 * c] = make_float4(vx, vy, vz, vw);
}

static inline size_t align256(size_t x) { return (x + 255) & ~(size_t)255; }

extern "C" void kernel_launch(void* const* d_in, const int* in_sizes, int n_in,
                              void* d_out, int out_size, void* d_ws, size_t ws_size,
                              hipStream_t stream) {
    const float* x  = (const float*)d_in[0];
    const float* W1 = (const float*)d_in[1];
    const float* b1 = (const float*)d_in[2];
    const float* W2 = (const float*)d_in[3];
    const float* b2 = (const float*)d_in[4];
    const float* W3 = (const float*)d_in[5];
    const float* b3 = (const float*)d_in[6];
    const int* edge = (const int*)d_in[7];

    int n = in_sizes[0] / 64;
    int E = in_sizes[7] / 2;
    const int* srcp = edge;
    const int* dstp = edge + E;

    int NB = (n + 255) >> SHIFT;              // buckets (391 for n=100000)
    int B1 = (E + CHUNK - 1) / CHUNK;         // hist/scatter blocks (391)

    char* ws = (char*)d_ws;
    int* row_ptr   = (int*)ws;      ws += align256((size_t)(n + 1) * 4);
    int* Bh        = (int*)ws;      ws += align256((size_t)B1 * NB * 4);
    int* Bc        = (int*)ws;      ws += align256((size_t)B1 * NB * 4);
    int* total     = (int*)ws;      ws += align256((size_t)NB * 4);
    unsigned* ebuf = (unsigned*)ws; ws += align256((size_t)E * 4);
    int* col       = (int*)ws;      ws += align256((size_t)E * 4);
    __half* hs_a   = (__half*)ws;   ws += align256((size_t)n * 64 * 2);
    __half* hs_b   = (__half*)ws;   ws += align256((size_t)n * 64 * 2);
    float* out     = (float*)d_out;

    // ---- CSR build: single cooperative kernel ----
    {
        int G = (B1 > NB) ? B1 : NB;
        int En = E, nn = n, NBn = NB, B1n = B1;
        const int* srcp_l = srcp;
        const int* dstp_l = dstp;
        int* Bh_l = Bh; int* Bc_l = Bc; int* total_l = total;
        unsigned* ebuf_l = ebuf; int* col_l = col; int* rp_l = row_ptr;
        void* args[] = {(void*)&srcp_l, (void*)&dstp_l, (void*)&En, (void*)&nn,
                        (void*)&NBn, (void*)&B1n, (void*)&Bh_l, (void*)&Bc_l,
                        (void*)&total_l, (void*)&ebuf_l, (void*)&col_l, (void*)&rp_l};
        hipLaunchCooperativeKernel((void*)k_build, dim3(G), dim3(256), args, 0, stream);
    }

    int blocks16 = (n + 15) / 16;   // 16 nodes per 256-thread block

    // layer 1 GEMM (MFMA): hs_a = fp16(dinv * (x @ W1))
    k_gemm_scale<<<blocks16, 256, 0, stream>>>(x, W1, row_ptr, n, hs_a);
    // layer 1 agg (+relu) fused with layer 2 GEMM (MFMA): hs_b
    k_agg_gemm<true><<<blocks16, 256, 0, stream>>>(hs_a, row_ptr, col, b1, W2, n, hs_b);
    // layer 2 agg (no act) fused with layer 3 GEMM (MFMA): hs_a
    k_agg_gemm<false><<<blocks16, 256, 0, stream>>>(hs_b, row_ptr, col, b2, W3, n, hs_a);
    // layer 3 agg + bias + relu -> out
    k_agg_out<<<blocks16, 256, 0, stream>>>(hs_a, row_ptr, col, b3, n, out);
}

// Round 13
// 158.388 us; speedup vs baseline: 1.9969x; 1.9969x over previous
//
#include <hip/hip_runtime.h>
#include <hip/hip_fp16.h>
#include <math.h>

// ---------------------------------------------------------------------------
// GCN 3-layer forward on MI355X.
// Per layer (D=64):
//   hs[i,:] = fp16( dinv[i] * (x[i,:] @ W) )
//   out[i,:]= dinv[i] * (hs[i,:] + sum_{e: dst(e)=i} hs[src(e),:]) + b
//   optional LeakyReLU(0.01);   dinv[i] = rsqrt(1 + indeg(i))
//
// Round-13: revert r12's cooperative build (172us: 1.5 blocks/CU co-residency
// starved latency hiding; grid.sync spin) back to r11's five separate build
// kernels (~35-40us).  KEEP r12's register B-fragment load (load_bfrag):
// r11's stage_wt cost 6M LDS-conflict cycles/dispatch (~25% of k_agg_gemm).
// Aggs (r8) remain at ~87% of the per-CU streaming byte rate.
// ---------------------------------------------------------------------------

constexpr int SHIFT = 8;          // bucket = dst >> 8  (256 nodes per bucket)
constexpr int CHUNK = 4096;       // edges per scatter block
constexpr int BCAP  = 5120;       // bucket staging capacity (mean 4096, sd 64)

typedef _Float16 half8 __attribute__((ext_vector_type(8)));
typedef float floatx4 __attribute__((ext_vector_type(4)));

// Exclusive scan of v over 256 threads (2 barriers).
__device__ inline int scan256(int v, int tid, int* wsum, int* total) {
    int lane = tid & 63, w = tid >> 6;
    int inc = v;
#pragma unroll
    for (int off = 1; off < 64; off <<= 1) {
        int t = __shfl_up(inc, off);
        if (lane >= off) inc += t;
    }
    if (lane == 63) wsum[w] = inc;
    __syncthreads();
    int s0 = wsum[0], s1 = wsum[1], s2 = wsum[2], s3 = wsum[3];
    __syncthreads();
    int base = (w > 0 ? s0 : 0) + (w > 1 ? s1 : 0) + (w > 2 ? s2 : 0);
    *total = s0 + s1 + s2 + s3;
    return base + (inc - v);
}

// ---- phase 1: per-block bucket histogram; Bh (to be scanned) + Bc (raw) ----
__global__ void k_hist(const int* __restrict__ dst, int E, int NB,
                       int* __restrict__ Bh, int* __restrict__ Bc) {
    __shared__ int h[512];
    int tid = threadIdx.x;
    for (int i = tid; i < 512; i += 256) h[i] = 0;
    __syncthreads();
    int s = blockIdx.x * CHUNK;
    int e = min(s + CHUNK, E);
    for (int i = s + tid; i < e; i += 256) atomicAdd(&h[dst[i] >> SHIFT], 1);
    __syncthreads();
    for (int i = tid; i < NB; i += 256) {
        int v = h[i];
        Bh[(size_t)blockIdx.x * NB + i] = v;
        Bc[(size_t)blockIdx.x * NB + i] = v;
    }
}

// ---- phase 1b: per-bucket exclusive scan down the block axis (in place) ----
__global__ void k_bucket_scan(int* __restrict__ Bh, int B1, int NB,
                              int* __restrict__ total) {
    __shared__ int wsum[4];
    int b = blockIdx.x;
    int tid = threadIdx.x;
    int carry = 0;
    for (int j0 = 0; j0 < B1; j0 += 256) {
        int j = j0 + tid;
        int v = (j < B1) ? Bh[(size_t)j * NB + b] : 0;
        int tot;
        int ex = scan256(v, tid, wsum, &tot);
        if (j < B1) Bh[(size_t)j * NB + b] = ex + carry;
        carry += tot;
    }
    if (tid == 0) total[b] = carry;
}

// ---- phase 1c: exclusive scan of bucket totals (NB <= 512), 256 threads ----
__global__ void k_base_scan(const int* __restrict__ total, int NB, int E,
                            int* __restrict__ base) {
    __shared__ int wsum[4];
    int tid = threadIdx.x;
    int b0 = 2 * tid, b1 = 2 * tid + 1;
    int v0 = (b0 < NB) ? total[b0] : 0;
    int v1 = (b1 < NB) ? total[b1] : 0;
    int tot;
    int ex = scan256(v0 + v1, tid, wsum, &tot);
    if (b0 < NB) base[b0] = ex;
    if (b1 < NB) base[b1] = ex + v0;
    if (tid == 0) base[NB] = E;
}

// ---- phase 2: LDS-binned scatter (local offsets from Bc, no re-histogram) --
// record = (dst & 255) << 24 | src      (src < 2^17)
__global__ void k_scatter(const int* __restrict__ src, const int* __restrict__ dst,
                          int E, int NB, const int* __restrict__ Bh,
                          const int* __restrict__ Bc, const int* __restrict__ base,
                          unsigned* __restrict__ ebuf) {
    __shared__ int cur[512];
    __shared__ int gb[512];
    __shared__ int wsum[4];
    __shared__ unsigned srec[CHUNK];
    __shared__ int spos[CHUNK];
    int tid = threadIdx.x;
    int j = blockIdx.x;

    int b0 = 2 * tid, b1 = 2 * tid + 1;
    int c0 = (b0 < NB) ? Bc[(size_t)j * NB + b0] : 0;
    int c1 = (b1 < NB) ? Bc[(size_t)j * NB + b1] : 0;
    int tot;
    int ex = scan256(c0 + c1, tid, wsum, &tot);
    if (b0 < NB) {
        cur[b0] = ex;
        gb[b0]  = base[b0] + Bh[(size_t)j * NB + b0] - ex;
    }
    if (b1 < NB) {
        int ex1 = ex + c0;
        cur[b1] = ex1;
        gb[b1]  = base[b1] + Bh[(size_t)j * NB + b1] - ex1;
    }
    __syncthreads();

    int s = j * CHUNK;
    int e = min(s + CHUNK, E);
    for (int i = s + tid; i < e; i += 256) {
        int d = dst[i];
        int b = d >> SHIFT;
        unsigned rec = ((unsigned)(d & 255) << 24) | (unsigned)src[i];
        int lpos = atomicAdd(&cur[b], 1);
        srec[lpos] = rec;
        spos[lpos] = gb[b] + lpos;
    }
    __syncthreads();
    int cntE = e - s;
    for (int t = tid; t < cntE; t += 256) ebuf[spos[t]] = srec[t];
}

// ---- phase 3: per-bucket counting sort, LDS-staged -> row_ptr + col --------
__global__ void k_bucket_sort(const unsigned* __restrict__ ebuf,
                              const int* __restrict__ base, int n, int E,
                              int* __restrict__ row_ptr, int* __restrict__ col) {
    __shared__ int cnt[256];
    __shared__ int cur[256];
    __shared__ int wsum[4];
    __shared__ unsigned raw[BCAP];
    __shared__ int sorted[BCAP];
    int b = blockIdx.x;
    int tid = threadIdx.x;
    int s = base[b];
    int e = base[b + 1];
    int len = e - s;
    cnt[tid] = 0;
    __syncthreads();
    if (len <= BCAP) {
        for (int t = tid; t < len; t += 256) {
            unsigned v = ebuf[s + t];   // single global read of the bucket
            raw[t] = v;
            atomicAdd(&cnt[v >> 24], 1);
        }
        __syncthreads();
        int tot;
        int ex = scan256(cnt[tid], tid, wsum, &tot);
        int node = (b << SHIFT) | tid;
        if (node < n) row_ptr[node] = s + ex;
        cur[tid] = ex;
        __syncthreads();
        for (int t = tid; t < len; t += 256) {
            unsigned v = raw[t];
            int lpos = atomicAdd(&cur[v >> 24], 1);
            sorted[lpos] = (int)((v & 0x00FFFFFFu) << 7);   // byte off: src*128
        }
        __syncthreads();
        for (int t = tid; t < len; t += 256) col[s + t] = sorted[t];
    } else {  // statistical-impossibility fallback: two-pass global
        for (int i = s + tid; i < e; i += 256) atomicAdd(&cnt[ebuf[i] >> 24], 1);
        __syncthreads();
        int tot;
        int ex = scan256(cnt[tid], tid, wsum, &tot);
        int node = (b << SHIFT) | tid;
        if (node < n) row_ptr[node] = s + ex;
        cur[tid] = ex;
        __syncthreads();
        for (int i = s + tid; i < e; i += 256) {
            unsigned v = ebuf[i];
            int lpos = atomicAdd(&cur[v >> 24], 1);
            col[s + lpos] = (int)((v & 0x00FFFFFFu) << 7);
        }
    }
    if (b == 0 && tid == 0) row_ptr[n] = E;
}

// ---- B-fragment (W columns) loaded straight from global into registers ----
// mfma_f32_16x16x32_f16 B layout: lane l holds B[k=(l>>4)*8+j][col=l&15];
// wave w covers output cols [16w,16w+16).  16 lanes read 64B/row -> coalesced;
// W is L2/L1-hot after the first wave.
__device__ inline void load_bfrag(const float* __restrict__ W, int tid,
                                  half8* b1, half8* b2) {
    int lane = tid & 63;
    int colg = (tid >> 6) * 16 + (lane & 15);
    int k0 = (lane >> 4) * 8;
    half8 x1, x2;
#pragma unroll
    for (int j = 0; j < 8; j++) {
        x1[j] = (_Float16)W[(k0 + j) * 64 + colg];
        x2[j] = (_Float16)W[(k0 + 32 + j) * 64 + colg];
    }
    *b1 = x1;
    *b2 = x2;
}

// ---- shared MFMA tail: rows(16x64 fp16 in LDS) x b-frags -> fp16 HS -------
__device__ inline void mfma_rows_store(const _Float16* rowS, const float* dinvS,
                                       half8 b1, half8 b2, int n, int blockRow0,
                                       int tid, __half* __restrict__ HSn) {
    int w = tid >> 6;
    int lane = tid & 63;
    int ar = lane & 15;
    int ks = lane >> 4;

    half8 a1 = *(const half8*)&rowS[ar * 72 + ks * 8];
    half8 a2 = *(const half8*)&rowS[ar * 72 + 32 + ks * 8];

    floatx4 acc = {0.f, 0.f, 0.f, 0.f};
    acc = __builtin_amdgcn_mfma_f32_16x16x32_f16(a1, b1, acc, 0, 0, 0);
    acc = __builtin_amdgcn_mfma_f32_16x16x32_f16(a2, b2, acc, 0, 0, 0);

    int node0 = (lane >> 4) * 4;
    float4 dv4 = *(const float4*)&dinvS[node0];
    int colg = w * 16 + (lane & 15);
    int base_node = blockRow0 + node0;
#pragma unroll
    for (int reg = 0; reg < 4; reg++) {
        int node_g = base_node + reg;
        if (node_g < n) {
            float dv = (reg == 0) ? dv4.x : (reg == 1) ? dv4.y : (reg == 2) ? dv4.z : dv4.w;
            HSn[(size_t)node_g * 64 + colg] = __float2half(acc[reg] * dv);
        }
    }
}

// ---- layer-1 GEMM via MFMA: HS = fp16(dinv * (X @ W)) ----------------------
__global__ void k_gemm_scale(const float* __restrict__ X, const float* __restrict__ W,
                             const int* __restrict__ row_ptr, int n,
                             __half* __restrict__ HS) {
    __shared__ _Float16 rowS[16 * 72];
    __shared__ float dinvS[16];
    int tid = threadIdx.x;

    half8 b1, b2;
    load_bfrag(W, tid, &b1, &b2);

    int g = tid >> 4;
    int c = tid & 15;
    int gid = blockIdx.x * 16 + g;
    if (gid < n) {
        float4 xv = *(const float4*)&X[(size_t)gid * 64 + c * 4];
        __half2 h0 = __floats2half2_rn(xv.x, xv.y);
        __half2 h1 = __floats2half2_rn(xv.z, xv.w);
        uint2 pack;
        pack.x = *(const unsigned int*)&h0;
        pack.y = *(const unsigned int*)&h1;
        *(uint2*)&rowS[g * 72 + c * 4] = pack;
        if (c == 0)
            dinvS[g] = rsqrtf(1.0f + (float)(row_ptr[gid + 1] - row_ptr[gid]));
    }
    __syncthreads();
    mfma_rows_store(rowS, dinvS, b1, b2, n, blockIdx.x * 16, tid, HS);
}

__device__ inline float4 cvt_h4(uint2 v) {
    float2 f0 = __half22float2(*(__half2*)&v.x);
    float2 f1 = __half22float2(*(__half2*)&v.y);
    return make_float4(f0.x, f0.y, f1.x, f1.y);
}

__device__ inline uint2 ld_row(const char* HSb, int boff, int c) {
    return *(const uint2*)(HSb + boff + (c << 3));
}

// Gather-aggregate one node's row: s = hs[self] + sum hs[src].  16-lane
// group, 8 gathers in flight (main), 4-batch, predicated singles.
__device__ inline float4 agg_row(const char* __restrict__ HSb,
                                 const int* __restrict__ col,
                                 int gid, int c, int r0, int r1) {
    float4 a0 = cvt_h4(*(const uint2*)(HSb + ((size_t)gid << 7) + (c << 3)));
    float4 a1 = make_float4(0.f, 0.f, 0.f, 0.f);
    float4 a2 = a1, a3 = a1;
    int e = r0;
    for (; e + 8 <= r1; e += 8) {
        int s0 = col[e + 0], s1 = col[e + 1], s2 = col[e + 2], s3 = col[e + 3];
        int s4 = col[e + 4], s5 = col[e + 5], s6 = col[e + 6], s7 = col[e + 7];
        uint2 v0 = ld_row(HSb, s0, c), v1 = ld_row(HSb, s1, c);
        uint2 v2 = ld_row(HSb, s2, c), v3 = ld_row(HSb, s3, c);
        uint2 v4 = ld_row(HSb, s4, c), v5 = ld_row(HSb, s5, c);
        uint2 v6 = ld_row(HSb, s6, c), v7 = ld_row(HSb, s7, c);
        float4 f0 = cvt_h4(v0), f1 = cvt_h4(v1), f2 = cvt_h4(v2), f3 = cvt_h4(v3);
        float4 f4 = cvt_h4(v4), f5 = cvt_h4(v5), f6 = cvt_h4(v6), f7 = cvt_h4(v7);
        a0.x += f0.x; a0.y += f0.y; a0.z += f0.z; a0.w += f0.w;
        a1.x += f1.x; a1.y += f1.y; a1.z += f1.z; a1.w += f1.w;
        a2.x += f2.x; a2.y += f2.y; a2.z += f2.z; a2.w += f2.w;
        a3.x += f3.x; a3.y += f3.y; a3.z += f3.z; a3.w += f3.w;
        a0.x += f4.x; a0.y += f4.y; a0.z += f4.z; a0.w += f4.w;
        a1.x += f5.x; a1.y += f5.y; a1.z += f5.z; a1.w += f5.w;
        a2.x += f6.x; a2.y += f6.y; a2.z += f6.z; a2.w += f6.w;
        a3.x += f7.x; a3.y += f7.y; a3.z += f7.z; a3.w += f7.w;
    }
    if (e + 4 <= r1) {
        int s0 = col[e + 0], s1 = col[e + 1], s2 = col[e + 2], s3 = col[e + 3];
        uint2 v0 = ld_row(HSb, s0, c), v1 = ld_row(HSb, s1, c);
        uint2 v2 = ld_row(HSb, s2, c), v3 = ld_row(HSb, s3, c);
        float4 f0 = cvt_h4(v0), f1 = cvt_h4(v1), f2 = cvt_h4(v2), f3 = cvt_h4(v3);
        a0.x += f0.x; a0.y += f0.y; a0.z += f0.z; a0.w += f0.w;
        a1.x += f1.x; a1.y += f1.y; a1.z += f1.z; a1.w += f1.w;
        a2.x += f2.x; a2.y += f2.y; a2.z += f2.z; a2.w += f2.w;
        a3.x += f3.x; a3.y += f3.y; a3.z += f3.z; a3.w += f3.w;
        e += 4;
    }
    if (e + 0 < r1) {
        float4 f = cvt_h4(ld_row(HSb, col[e + 0], c));
        a0.x += f.x; a0.y += f.y; a0.z += f.z; a0.w += f.w;
    }
    if (e + 1 < r1) {
        float4 f = cvt_h4(ld_row(HSb, col[e + 1], c));
        a1.x += f.x; a1.y += f.y; a1.z += f.z; a1.w += f.w;
    }
    if (e + 2 < r1) {
        float4 f = cvt_h4(ld_row(HSb, col[e + 2], c));
        a2.x += f.x; a2.y += f.y; a2.z += f.z; a2.w += f.w;
    }
    float4 s;
    s.x = (a0.x + a1.x) + (a2.x + a3.x);
    s.y = (a0.y + a1.y) + (a2.y + a3.y);
    s.z = (a0.z + a1.z) + (a2.z + a3.z);
    s.w = (a0.w + a1.w) + (a2.w + a3.w);
    return s;
}

// ---- fused: agg epilogue + next-layer GEMM (MFMA) -> fp16 hs_next ---------
template <bool RELU>
__global__ void k_agg_gemm(const __half* __restrict__ HS, const int* __restrict__ row_ptr,
                           const int* __restrict__ col, const float* __restrict__ bias,
                           const float* __restrict__ Wn, int n,
                           __half* __restrict__ HSn) {
    __shared__ _Float16 rowS[16 * 72];
    __shared__ float dinvS[16];
    int tid = threadIdx.x;

    half8 b1, b2;
    load_bfrag(Wn, tid, &b1, &b2);

    int g = tid >> 4;
    int c = tid & 15;
    int gid = blockIdx.x * 16 + g;

    if (gid < n) {
        const char* __restrict__ HSb = (const char*)HS;
        int r0 = row_ptr[gid];
        int r1 = row_ptr[gid + 1];
        float4 s = agg_row(HSb, col, gid, c, r0, r1);
        float deg = 1.0f + (float)(r1 - r0);
        float dinv = rsqrtf(deg);
        float4 bv = *(const float4*)&bias[4 * c];
        float vx = dinv * s.x + bv.x;
        float vy = dinv * s.y + bv.y;
        float vz = dinv * s.z + bv.z;
        float vw = dinv * s.w + bv.w;
        if (RELU) {
            vx = (vx >= 0.f) ? vx : 0.01f * vx;
            vy = (vy >= 0.f) ? vy : 0.01f * vy;
            vz = (vz >= 0.f) ? vz : 0.01f * vz;
            vw = (vw >= 0.f) ? vw : 0.01f * vw;
        }
        __half2 h0 = __floats2half2_rn(vx, vy);
        __half2 h1 = __floats2half2_rn(vz, vw);
        uint2 pack;
        pack.x = *(const unsigned int*)&h0;
        pack.y = *(const unsigned int*)&h1;
        *(uint2*)&rowS[g * 72 + c * 4] = pack;
        if (c == 0) dinvS[g] = dinv;
    }
    __syncthreads();
    mfma_rows_store(rowS, dinvS, b1, b2, n, blockIdx.x * 16, tid, HSn);
}

// ---- final layer: agg + bias + LeakyReLU -> fp32 out ----------------------
__global__ void k_agg_out(const __half* __restrict__ HS, const int* __restrict__ row_ptr,
                          const int* __restrict__ col, const float* __restrict__ bias,
                          int n, float* __restrict__ out) {
    int gid = (int)((blockIdx.x * (unsigned)blockDim.x + threadIdx.x) >> 4);
    if (gid >= n) return;
    int c = threadIdx.x & 15;
    const char* __restrict__ HSb = (const char*)HS;
    int r0 = row_ptr[gid];
    int r1 = row_ptr[gid + 1];
    float4 s = agg_row(HSb, col, gid, c, r0, r1);
    float deg = 1.0f + (float)(r1 - r0);
    float dinv = rsqrtf(deg);
    float4 bv = *(const float4*)&bias[4 * c];
    float vx = dinv * s.x + bv.x;
    float vy = dinv * s.y + bv.y;
    float vz = dinv * s.z + bv.z;
    float vw = dinv * s.w + bv.w;
    vx = (vx >= 0.f) ? vx : 0.01f * vx;
    vy = (vy >= 0.f) ? vy : 0.01f * vy;
    vz = (vz >= 0.f) ? vz : 0.01f * vz;
    vw = (vw >= 0.f) ? vw : 0.01f * vw;
    *(float4*)&out[(size_t)gid * 64 + 4 * c] = make_float4(vx, vy, vz, vw);
}

static inline size_t align256(size_t x) { return (x + 255) & ~(size_t)255; }

extern "C" void kernel_launch(void* const* d_in, const int* in_sizes, int n_in,
                              void* d_out, int out_size, void* d_ws, size_t ws_size,
                              hipStream_t stream) {
    const float* x  = (const float*)d_in[0];
    const float* W1 = (const float*)d_in[1];
    const float* b1 = (const float*)d_in[2];
    const float* W2 = (const float*)d_in[3];
    const float* b2 = (const float*)d_in[4];
    const float* W3 = (const float*)d_in[5];
    const float* b3 = (const float*)d_in[6];
    const int* edge = (const int*)d_in[7];

    int n = in_sizes[0] / 64;
    int E = in_sizes[7] / 2;
    const int* srcp = edge;
    const int* dstp = edge + E;

    int NB = (n + 255) >> SHIFT;              // buckets (391 for n=100000)
    int B1 = (E + CHUNK - 1) / CHUNK;         // histogram/scatter blocks

    char* ws = (char*)d_ws;
    int* row_ptr   = (int*)ws;      ws += align256((size_t)(n + 1) * 4);
    int* Bh        = (int*)ws;      ws += align256((size_t)B1 * NB * 4);
    int* Bc        = (int*)ws;      ws += align256((size_t)B1 * NB * 4);
    int* total     = (int*)ws;      ws += align256((size_t)NB * 4);
    int* base      = (int*)ws;      ws += align256((size_t)(NB + 1) * 4);
    unsigned* ebuf = (unsigned*)ws; ws += align256((size_t)E * 4);
    int* col       = (int*)ws;      ws += align256((size_t)E * 4);
    __half* hs_a   = (__half*)ws;   ws += align256((size_t)n * 64 * 2);
    __half* hs_b   = (__half*)ws;   ws += align256((size_t)n * 64 * 2);
    float* out     = (float*)d_out;

    // ---- CSR build: two-level bucket sort (shfl scans, LDS-binned writes) --
    k_hist<<<B1, 256, 0, stream>>>(dstp, E, NB, Bh, Bc);
    k_bucket_scan<<<NB, 256, 0, stream>>>(Bh, B1, NB, total);
    k_base_scan<<<1, 256, 0, stream>>>(total, NB, E, base);
    k_scatter<<<B1, 256, 0, stream>>>(srcp, dstp, E, NB, Bh, Bc, base, ebuf);
    k_bucket_sort<<<NB, 256, 0, stream>>>(ebuf, base, n, E, row_ptr, col);

    int blocks16 = (n + 15) / 16;   // 16 nodes per 256-thread block

    // layer 1 GEMM (MFMA): hs_a = fp16(dinv * (x @ W1))
    k_gemm_scale<<<blocks16, 256, 0, stream>>>(x, W1, row_ptr, n, hs_a);
    // layer 1 agg (+relu) fused with layer 2 GEMM (MFMA): hs_b
    k_agg_gemm<true><<<blocks16, 256, 0, stream>>>(hs_a, row_ptr, col, b1, W2, n, hs_b);
    // layer 2 agg (no act) fused with layer 3 GEMM (MFMA): hs_a
    k_agg_gemm<false><<<blocks16, 256, 0, stream>>>(hs_b, row_ptr, col, b2, W3, n, hs_a);
    // layer 3 agg + bias + relu -> out
    k_agg_out<<<blocks16, 256, 0, stream>>>(hs_a, row_ptr, col, b3, n, out);
}